// Round 8
// baseline (222.986 us; speedup 1.0000x reference)
//
#include <hip/hip_runtime.h>
#include <math.h>

#define B_ 8
#define CIN_ 512
#define K_ 64
#define V_ 256
#define T_ 1024
#define KS_ 23
#define EPS_ 1e-5f

typedef __attribute__((ext_vector_type(8))) short bf16x8;
typedef __attribute__((ext_vector_type(4))) float f32x4;

__device__ __forceinline__ unsigned short f2bf(float f) {
    union { float f; unsigned u; } x; x.f = f;
    unsigned r = x.u + 0x7fffu + ((x.u >> 16) & 1u);   // RNE
    return (unsigned short)(r >> 16);
}
__device__ __forceinline__ float bf2f(unsigned short h) {
    union { unsigned u; float f; } x; x.u = ((unsigned)h) << 16;
    return x.f;
}

// ---------------------------------------------------------------------------
// prep: merged cvtT (blocks 0..2047) + prew (blocks 2048..2239).
// cvtT: src[b][c][t] f32 -> dst[b][t][c] bf16, 64x64 LDS tiles.
// prew: Wq|Wk|Wv fp32 -> bf16 concat; block 2048 zeroes stat[640].
// ---------------------------------------------------------------------------
__global__ __launch_bounds__(256) void prep_kernel(
    const float* __restrict__ x, const float* __restrict__ ctx,
    const float* __restrict__ Wq, const float* __restrict__ Wk,
    const float* __restrict__ Wv,
    unsigned short* __restrict__ xT, unsigned short* __restrict__ cT,
    unsigned short* __restrict__ Wb, float* __restrict__ stat)
{
    __shared__ unsigned short sh[64][72];
    const int tid = threadIdx.x;
    const int id = blockIdx.x;
    if (id < 2048) {
        const int t0 = (id & 15) * 64, c0 = ((id >> 4) & 7) * 64;
        const int z = id >> 7, b = z & 7, which = z >> 3;
        const float* src = which ? ctx : x;
        unsigned short* dst = which ? cT : xT;
        const int cl = tid >> 2, qq = tid & 3;
        const float* row = src + ((size_t)b * CIN_ + c0 + cl) * T_ + t0 + qq * 16;
        #pragma unroll
        for (int u = 0; u < 4; u++) {
            float4 f = *(const float4*)(row + 4 * u);
            sh[qq * 16 + 4 * u + 0][cl] = f2bf(f.x);
            sh[qq * 16 + 4 * u + 1][cl] = f2bf(f.y);
            sh[qq * 16 + 4 * u + 2][cl] = f2bf(f.z);
            sh[qq * 16 + 4 * u + 3][cl] = f2bf(f.w);
        }
        __syncthreads();
        const int tl = tid >> 2;
        unsigned short* orow = dst + ((size_t)b * T_ + t0 + tl) * CIN_ + c0 + qq * 16;
        *(bf16x8*)(orow)     = *(bf16x8*)&sh[tl][qq * 16];
        *(bf16x8*)(orow + 8) = *(bf16x8*)&sh[tl][qq * 16 + 8];
    } else {
        const int wid = id - 2048;
        if (wid == 0 && tid < 160)
            ((float4*)stat)[tid] = make_float4(0.f, 0.f, 0.f, 0.f);
        const int i4 = wid * 256 + tid;
        const int n1 = K_ * CIN_ / 4, n2 = 2 * K_ * CIN_ / 4;
        const float* src; int off;
        if (i4 < n1)      { src = Wq; off = i4; }
        else if (i4 < n2) { src = Wk; off = i4 - n1; }
        else              { src = Wv; off = i4 - n2; }
        float4 f = ((const float4*)src)[off];
        ushort4 h;
        h.x = f2bf(f.x); h.y = f2bf(f.y); h.z = f2bf(f.z); h.w = f2bf(f.w);
        *(ushort4*)(Wb + (size_t)i4 * 4) = h;
    }
}

// ---------------------------------------------------------------------------
// proj_mfma3: bf16 MFMA projection + fused BN channel stats (atomics).
// yb: 0 = q -> qT bf16 + q stats; 1 = k -> k_buf fp32; 2..5 = v + v stats
// stat: [0:64) qsum, [64:128) qsq, [128:384) vsum, [384:640) vsq
// ---------------------------------------------------------------------------
__global__ __launch_bounds__(256) void proj_mfma3(
    const unsigned short* __restrict__ xT, const unsigned short* __restrict__ cT,
    const unsigned short* __restrict__ Wb,
    const float* __restrict__ bq, const float* __restrict__ bk,
    const float* __restrict__ bv,
    float* __restrict__ k_buf, float* __restrict__ v_raw,
    unsigned short* __restrict__ qT, float* __restrict__ stat)
{
    __shared__ unsigned short Wt[64][72];
    __shared__ unsigned short Xt[128][72];
    const int tid = threadIdx.x;
    const int b = blockIdx.z, t0 = blockIdx.x * 128, yb = blockIdx.y;

    const unsigned short* in; const unsigned short* W; const float* bias;
    float* outp = nullptr; int ch0 = 0; float* ssum = nullptr; float* ssq = nullptr;
    if (yb == 0)      { in = xT; W = Wb;             bias = bq;
                        ssum = stat; ssq = stat + 64; ch0 = 0; }
    else if (yb == 1) { in = cT; W = Wb + K_ * CIN_; bias = bk;
                        outp = k_buf + (size_t)b * K_ * T_; }
    else { int m0 = (yb - 2) * 64; in = cT;
           W = Wb + 2 * K_ * CIN_ + (size_t)m0 * CIN_; bias = bv + m0;
           outp = v_raw + ((size_t)b * V_ + m0) * T_;
           ssum = stat + 128; ssq = stat + 384; ch0 = m0; }

    const int lane = tid & 63, w = tid >> 6;
    const int col = lane & 15, quad = lane >> 4;
    const int wm = tid >> 2, wp = tid & 3;
    const int xt = tid >> 1, xh = tid & 1;

    f32x4 acc[8];
    #pragma unroll
    for (int j = 0; j < 8; j++) acc[j] = (f32x4){0.f, 0.f, 0.f, 0.f};

    for (int c0 = 0; c0 < CIN_; c0 += 64) {
        {
            const unsigned short* ws = W + (size_t)wm * CIN_ + c0 + wp * 16;
            *(bf16x8*)&Wt[wm][wp * 16]     = *(const bf16x8*)(ws);
            *(bf16x8*)&Wt[wm][wp * 16 + 8] = *(const bf16x8*)(ws + 8);
            const unsigned short* xs = in + ((size_t)b * T_ + t0 + xt) * CIN_ + c0 + xh * 32;
            #pragma unroll
            for (int u = 0; u < 4; u++)
                *(bf16x8*)&Xt[xt][xh * 32 + 8 * u] = *(const bf16x8*)(xs + 8 * u);
        }
        __syncthreads();
        #pragma unroll
        for (int ks = 0; ks < 2; ks++) {
            const int kc = ks * 32 + quad * 8;
            bf16x8 af = *(bf16x8*)&Wt[w * 16 + col][kc];
            #pragma unroll
            for (int j = 0; j < 8; j++) {
                bf16x8 bfr = *(bf16x8*)&Xt[j * 16 + col][kc];
                acc[j] = __builtin_amdgcn_mfma_f32_16x16x32_bf16(af, bfr, acc[j], 0, 0, 0);
            }
        }
        __syncthreads();
    }

    float bias_v[4], s[4], sq[4];
    #pragma unroll
    for (int r = 0; r < 4; r++) {
        bias_v[r] = bias[w * 16 + quad * 4 + r];
        s[r] = 0.f; sq[r] = 0.f;
    }
    #pragma unroll
    for (int j = 0; j < 8; j++) {
        float o[4];
        #pragma unroll
        for (int r = 0; r < 4; r++) {
            o[r] = acc[j][r] + bias_v[r];
            s[r] += o[r]; sq[r] += o[r] * o[r];
        }
        if (yb == 0) {
            ushort4 h;
            h.x = f2bf(o[0]); h.y = f2bf(o[1]); h.z = f2bf(o[2]); h.w = f2bf(o[3]);
            *(ushort4*)(qT + ((size_t)b * T_ + t0 + j * 16 + col) * K_ + w * 16 + quad * 4) = h;
        } else {
            #pragma unroll
            for (int r = 0; r < 4; r++)
                outp[(size_t)(w * 16 + quad * 4 + r) * T_ + t0 + j * 16 + col] = o[r];
        }
    }
    if (ssum) {
        #pragma unroll
        for (int r = 0; r < 4; r++) {
            float sv = s[r], qv = sq[r];
            #pragma unroll
            for (int off = 1; off < 16; off <<= 1) {
                sv += __shfl_xor(sv, off, 64);
                qv += __shfl_xor(qv, off, 64);
            }
            if (col == 0) {
                int ch = ch0 + w * 16 + quad * 4 + r;
                atomicAdd(&ssum[ch], sv);
                atomicAdd(&ssq[ch], qv);
            }
        }
    }
}

// ---------------------------------------------------------------------------
// slc: fused softmax + lambda + BN/prep_cl.  Grid (V_/64, B_) = 32 blocks.
// Phase 1: online softmax (m, 1/l) per k-row from k_buf (no writeback).
// Phase 2: cl[k][v] = sum_t softmax(k)[t]*v_raw[v][t], 16 t-chunk LDS tiles,
//          full-T accumulation in registers (no clp round-trip).
// Phase 3: BN inline -> clb2 bf16 [b][v][k] (*qsc[k]) + hterm[b][v].
// ---------------------------------------------------------------------------
__global__ __launch_bounds__(256) void slc_kernel(
    const float* __restrict__ k_buf, const float* __restrict__ v_raw,
    const float* __restrict__ stat,
    const float* __restrict__ gq, const float* __restrict__ betaq,
    const float* __restrict__ gv, const float* __restrict__ betav,
    unsigned short* __restrict__ clb2, float* __restrict__ hterm)
{
    __shared__ __align__(16) float nks[K_][68];
    __shared__ __align__(16) float vls[64][68];
    __shared__ float mrow[64], lrow[64];
    __shared__ float ml4[64][4][2];
    __shared__ float qsc[64], qsh[64];
    __shared__ float redh[16][68];
    const int tid = threadIdx.x;
    const int b = blockIdx.y, v0 = blockIdx.x * 64;
    const float inv_n = 1.f / (B_ * T_);

    if (tid < 64) {
        float mean = stat[tid] * inv_n;
        float var  = stat[64 + tid] * inv_n - mean * mean;
        float sc = gq[tid] * rsqrtf(var + EPS_);
        qsc[tid] = sc; qsh[tid] = betaq[tid] - mean * sc;
    }

    // ---- phase 1: online softmax stats, 4 threads per row ----
    {
        const int r = tid >> 2, j = tid & 3;
        const float4* krow = (const float4*)(k_buf + ((size_t)b * K_ + r) * T_);
        float m = -1e30f, l = 0.f;
        for (int i = 0; i < 64; i++) {
            float4 v = krow[j + 4 * i];
            float mx = fmaxf(fmaxf(v.x, v.y), fmaxf(v.z, v.w));
            float mn = fmaxf(m, mx);
            l = l * __expf(m - mn) + __expf(v.x - mn) + __expf(v.y - mn)
              + __expf(v.z - mn) + __expf(v.w - mn);
            m = mn;
        }
        ml4[r][j][0] = m; ml4[r][j][1] = l;
    }
    __syncthreads();
    if (tid < 64) {
        float mm = -1e30f;
        #pragma unroll
        for (int u = 0; u < 4; u++) mm = fmaxf(mm, ml4[tid][u][0]);
        float ll = 0.f;
        #pragma unroll
        for (int u = 0; u < 4; u++) ll += ml4[tid][u][1] * __expf(ml4[tid][u][0] - mm);
        mrow[tid] = mm; lrow[tid] = 1.f / ll;
    }
    __syncthreads();

    // ---- phase 2: lambda accumulation over 16 t-chunks ----
    const int tv = tid & 15, tk = tid >> 4;
    float4 acc[4];
    #pragma unroll
    for (int i = 0; i < 4; i++) acc[i] = make_float4(0.f, 0.f, 0.f, 0.f);

    for (int tc = 0; tc < 16; tc++) {
        const int t0 = tc * 64;
        {
            const int rr = tid >> 2, q = tid & 3;
            const float* nrow = k_buf + ((size_t)b * K_ + rr) * T_ + t0;
            const float* vrow = v_raw + ((size_t)b * V_ + v0 + rr) * T_ + t0;
            const float mr = mrow[rr], li = lrow[rr];
            #pragma unroll
            for (int i = 0; i < 4; i++) {
                int c4 = q + 4 * i;
                float4 g = *(const float4*)(nrow + 4 * c4);
                g.x = __expf(g.x - mr) * li; g.y = __expf(g.y - mr) * li;
                g.z = __expf(g.z - mr) * li; g.w = __expf(g.w - mr) * li;
                *(float4*)&nks[rr][4 * c4] = g;
                float4 h = *(const float4*)(vrow + 4 * c4);
                vls[4 * c4 + 0][rr] = h.x; vls[4 * c4 + 1][rr] = h.y;
                vls[4 * c4 + 2][rr] = h.z; vls[4 * c4 + 3][rr] = h.w;
            }
        }
        __syncthreads();
        for (int tt = 0; tt < 16; tt++) {
            float4 w0 = *(float4*)&vls[4 * tt + 0][4 * tv];
            float4 w1 = *(float4*)&vls[4 * tt + 1][4 * tv];
            float4 w2 = *(float4*)&vls[4 * tt + 2][4 * tv];
            float4 w3 = *(float4*)&vls[4 * tt + 3][4 * tv];
            #pragma unroll
            for (int i = 0; i < 4; i++) {
                float4 n = *(float4*)&nks[4 * tk + i][4 * tt];
                acc[i] += w0 * n.x + w1 * n.y + w2 * n.z + w3 * n.w;
            }
        }
        __syncthreads();
    }

    // ---- phase 3: BN + clb2 + hterm ----
    const int cb = v0 + 4 * tv;
    float vsv[4], vhv[4];
    #pragma unroll
    for (int jj = 0; jj < 4; jj++) {
        int c = cb + jj;
        float mean = stat[128 + c] * inv_n;
        float var  = stat[384 + c] * inv_n - mean * mean;
        vsv[jj] = gv[c] * rsqrtf(var + EPS_);
        vhv[jj] = betav[c] - mean * vsv[jj];
    }
    float hpart[4] = {0.f, 0.f, 0.f, 0.f};
    #pragma unroll
    for (int i = 0; i < 4; i++) {
        int k = 4 * tk + i;
        float* ap = (float*)&acc[i];
        #pragma unroll
        for (int jj = 0; jj < 4; jj++) {
            float clbv = ap[jj] * vsv[jj] + vhv[jj];
            hpart[jj] += qsh[k] * clbv;
            clb2[((size_t)b * V_ + cb + jj) * K_ + k] = f2bf(clbv * qsc[k]);
        }
    }
    #pragma unroll
    for (int jj = 0; jj < 4; jj++) redh[tk][4 * tv + jj] = hpart[jj];
    __syncthreads();
    if (tid < 64) {
        float h = 0.f;
        #pragma unroll
        for (int u = 0; u < 16; u++) h += redh[u][tid];
        hterm[(size_t)b * V_ + v0 + tid] = h;
    }
}

// ---------------------------------------------------------------------------
// out4: fused qp + content-MFMA + conv epilogue (unchanged from R7).
// ---------------------------------------------------------------------------
__global__ __launch_bounds__(256) void out_kernel4(
    const unsigned short* __restrict__ qT, const unsigned short* __restrict__ clb2,
    const float* __restrict__ hterm, const float* __restrict__ v_raw,
    const float* __restrict__ stat,
    const float* __restrict__ gq, const float* __restrict__ betaq,
    const float* __restrict__ gv, const float* __restrict__ betav,
    const float* __restrict__ pos_w, const float* __restrict__ pos_b,
    float* __restrict__ out)
{
    __shared__ unsigned short qTt[64][72];
    __shared__ unsigned short clv[64][72];
    __shared__ float vs2T[88][68];
    __shared__ float qpt[64][24];
    __shared__ float pws[64][24];
    __shared__ float qsc[64], qsh[64];
    __shared__ float consts[24];
    __shared__ float hvs[64];
    const int tid = threadIdx.x;
    const int b = blockIdx.z, v0 = blockIdx.y * 64, t0 = blockIdx.x * 64;
    const float inv_n = 1.f / (B_ * T_);

    if (tid < 64) {
        float mean = stat[tid] * inv_n;
        float var  = stat[64 + tid] * inv_n - mean * mean;
        float sc = gq[tid] * rsqrtf(var + EPS_);
        qsc[tid] = sc; qsh[tid] = betaq[tid] - mean * sc;
        hvs[tid] = hterm[(size_t)b * V_ + v0 + tid];
    }
    {
        const int rl = tid >> 2, part = tid & 3;
        const unsigned short* qs = qT + ((size_t)b * T_ + t0 + rl) * K_ + part * 16;
        *(bf16x8*)&qTt[rl][part * 16]     = *(const bf16x8*)(qs);
        *(bf16x8*)&qTt[rl][part * 16 + 8] = *(const bf16x8*)(qs + 8);
        const unsigned short* cs = clb2 + ((size_t)b * V_ + v0 + rl) * K_ + part * 16;
        *(bf16x8*)&clv[rl][part * 16]     = *(const bf16x8*)(cs);
        *(bf16x8*)&clv[rl][part * 16 + 8] = *(const bf16x8*)(cs + 8);
    }
    {
        const int vl = tid >> 2, qq = tid & 3;
        const int c = v0 + vl;
        float vmean = stat[128 + c] * inv_n;
        float vvar  = stat[384 + c] * inv_n - vmean * vmean;
        float vsv = gv[c] * rsqrtf(vvar + EPS_);
        float vhv = betav[c] - vmean * vsv;
        const float* vrow = v_raw + ((size_t)b * V_ + c) * T_;
        #pragma unroll
        for (int i = 0; i < 22; i++) {
            int cc = qq + 4 * i;
            if (cc < 86) {
                int t = t0 + cc - 11;
                vs2T[cc][vl] = (t >= 0 && t < T_) ? vrow[t] * vsv + vhv : 0.f;
            }
        }
    }
    __syncthreads();

    for (int idx = tid; idx < K_ * 24; idx += 256) {
        int k = idx / 24, s = idx % 24;
        pws[k][s] = qsc[k] * (s < KS_ ? pos_w[k * KS_ + s] : pos_b[k]);
    }
    if (tid < 24) {
        float cs = 0.f;
        for (int k = 0; k < K_; k++)
            cs += qsh[k] * (tid < KS_ ? pos_w[k * KS_ + tid] : pos_b[k]);
        consts[tid] = cs;
    }
    __syncthreads();

    {
        const int t = tid >> 2, sg = tid & 3, s0 = sg * 6;
        float a[6];
        #pragma unroll
        for (int u = 0; u < 6; u++) a[u] = consts[s0 + u];
        #pragma unroll
        for (int kb = 0; kb < 8; kb++) {
            bf16x8 qv = *(bf16x8*)&qTt[t][kb * 8];
            #pragma unroll
            for (int j = 0; j < 8; j++) {
                float q = bf2f((unsigned short)qv[j]);
                #pragma unroll
                for (int u = 0; u < 6; u++) a[u] += q * pws[kb * 8 + j][s0 + u];
            }
        }
        #pragma unroll
        for (int u = 0; u < 6; u++) qpt[t][s0 + u] = a[u];
    }
    __syncthreads();

    const int lane = tid & 63, w = tid >> 6;
    const int col = lane & 15, quad = lane >> 4;

    f32x4 acc[4];
    #pragma unroll
    for (int tf = 0; tf < 4; tf++) acc[tf] = (f32x4){0.f, 0.f, 0.f, 0.f};

    #pragma unroll
    for (int ks = 0; ks < 2; ks++) {
        const int kc = ks * 32 + quad * 8;
        bf16x8 af = *(bf16x8*)&clv[w * 16 + col][kc];
        #pragma unroll
        for (int tf = 0; tf < 4; tf++) {
            bf16x8 bq = *(bf16x8*)&qTt[tf * 16 + col][kc];
            acc[tf] = __builtin_amdgcn_mfma_f32_16x16x32_bf16(af, bq, acc[tf], 0, 0, 0);
        }
    }

    const int vb = w * 16 + quad * 4;
    float4 hv4 = *(float4*)&hvs[vb];
    #pragma unroll
    for (int tf = 0; tf < 4; tf++) {
        const int lt = tf * 16 + col;
        float qv[24];
        #pragma unroll
        for (int u = 0; u < 6; u++)
            *(float4*)&qv[4 * u] = *(float4*)&qpt[lt][4 * u];
        float4 a; a.x = acc[tf][0]; a.y = acc[tf][1]; a.z = acc[tf][2]; a.w = acc[tf][3];
        #pragma unroll
        for (int s = 0; s < KS_; s++) {
            float4 wv = *(float4*)&vs2T[lt + s][vb];
            a.x += qv[s] * wv.x; a.y += qv[s] * wv.y;
            a.z += qv[s] * wv.z; a.w += qv[s] * wv.w;
        }
        float base = qv[23];
        a.x += base + hv4.x; a.y += base + hv4.y;
        a.z += base + hv4.z; a.w += base + hv4.w;
        float* ap = (float*)&a;
        #pragma unroll
        for (int r = 0; r < 4; r++)
            out[((size_t)b * V_ + v0 + vb + r) * T_ + t0 + lt] = ap[r];
    }
}

extern "C" void kernel_launch(void* const* d_in, const int* in_sizes, int n_in,
                              void* d_out, int out_size, void* d_ws, size_t ws_size,
                              hipStream_t stream)
{
    const float* x     = (const float*)d_in[0];
    const float* ctx   = (const float*)d_in[1];
    const float* Wq    = (const float*)d_in[2];
    const float* bq    = (const float*)d_in[3];
    const float* Wk    = (const float*)d_in[4];
    const float* bk    = (const float*)d_in[5];
    const float* Wv    = (const float*)d_in[6];
    const float* bv    = (const float*)d_in[7];
    const float* gq    = (const float*)d_in[8];
    const float* betaq = (const float*)d_in[9];
    const float* gv    = (const float*)d_in[10];
    const float* betav = (const float*)d_in[11];
    const float* pos_w = (const float*)d_in[12];
    const float* pos_b = (const float*)d_in[13];
    float* out = (float*)d_out;

    float* ws    = (float*)d_ws;
    float* k_buf = ws;                                   // B*K*T = 524288
    float* v_raw = k_buf + (size_t)B_ * K_ * T_;         // B*V*T = 2097152
    float* stat  = v_raw + (size_t)B_ * V_ * T_;         // 640
    float* hterm = stat + 640;                           // B*V = 2048
    unsigned short* xT   = (unsigned short*)(hterm + (size_t)B_ * V_);
    unsigned short* cT   = xT + (size_t)B_ * T_ * CIN_;
    unsigned short* Wb   = cT + (size_t)B_ * T_ * CIN_;
    unsigned short* qT   = Wb + (size_t)(2 * K_ + V_) * CIN_;
    unsigned short* clb2 = qT + (size_t)B_ * T_ * K_;

    prep_kernel<<<dim3(2048 + 192), 256, 0, stream>>>(
        x, ctx, Wq, Wk, Wv, xT, cT, Wb, stat);
    proj_mfma3<<<dim3(T_ / 128, 6, B_), 256, 0, stream>>>(
        xT, cT, Wb, bq, bk, bv, k_buf, v_raw, qT, stat);
    slc_kernel<<<dim3(V_ / 64, B_), 256, 0, stream>>>(
        k_buf, v_raw, stat, gq, betaq, gv, betav, clb2, hterm);
    out_kernel4<<<dim3(T_ / 64, V_ / 64, B_), 256, 0, stream>>>(
        qT, clb2, hterm, v_raw, stat, gq, betaq, gv, betav, pos_w, pos_b, out);
}

// Round 9
// 160.420 us; speedup vs baseline: 1.3900x; 1.3900x over previous
//
#include <hip/hip_runtime.h>
#include <math.h>

#define B_ 8
#define CIN_ 512
#define K_ 64
#define V_ 256
#define T_ 1024
#define KS_ 23
#define EPS_ 1e-5f
#define NTC_ 16   // lambda t-chunks (partials)

typedef __attribute__((ext_vector_type(8))) short bf16x8;
typedef __attribute__((ext_vector_type(4))) float f32x4;

__device__ __forceinline__ unsigned short f2bf(float f) {
    union { float f; unsigned u; } x; x.f = f;
    unsigned r = x.u + 0x7fffu + ((x.u >> 16) & 1u);   // RNE
    return (unsigned short)(r >> 16);
}
__device__ __forceinline__ float bf2f(unsigned short h) {
    union { unsigned u; float f; } x; x.u = ((unsigned)h) << 16;
    return x.f;
}

// ---------------------------------------------------------------------------
// prep: merged cvtT (blocks 0..2047) + prew (blocks 2048..2239).
// ---------------------------------------------------------------------------
__global__ __launch_bounds__(256) void prep_kernel(
    const float* __restrict__ x, const float* __restrict__ ctx,
    const float* __restrict__ Wq, const float* __restrict__ Wk,
    const float* __restrict__ Wv,
    unsigned short* __restrict__ xT, unsigned short* __restrict__ cT,
    unsigned short* __restrict__ Wb, float* __restrict__ stat)
{
    __shared__ unsigned short sh[64][72];
    const int tid = threadIdx.x;
    const int id = blockIdx.x;
    if (id < 2048) {
        const int t0 = (id & 15) * 64, c0 = ((id >> 4) & 7) * 64;
        const int z = id >> 7, b = z & 7, which = z >> 3;
        const float* src = which ? ctx : x;
        unsigned short* dst = which ? cT : xT;
        const int cl = tid >> 2, qq = tid & 3;
        const float* row = src + ((size_t)b * CIN_ + c0 + cl) * T_ + t0 + qq * 16;
        #pragma unroll
        for (int u = 0; u < 4; u++) {
            float4 f = *(const float4*)(row + 4 * u);
            sh[qq * 16 + 4 * u + 0][cl] = f2bf(f.x);
            sh[qq * 16 + 4 * u + 1][cl] = f2bf(f.y);
            sh[qq * 16 + 4 * u + 2][cl] = f2bf(f.z);
            sh[qq * 16 + 4 * u + 3][cl] = f2bf(f.w);
        }
        __syncthreads();
        const int tl = tid >> 2;
        unsigned short* orow = dst + ((size_t)b * T_ + t0 + tl) * CIN_ + c0 + qq * 16;
        *(bf16x8*)(orow)     = *(bf16x8*)&sh[tl][qq * 16];
        *(bf16x8*)(orow + 8) = *(bf16x8*)&sh[tl][qq * 16 + 8];
    } else {
        const int wid = id - 2048;
        if (wid == 0 && tid < 160)
            ((float4*)stat)[tid] = make_float4(0.f, 0.f, 0.f, 0.f);
        const int i4 = wid * 256 + tid;
        const int n1 = K_ * CIN_ / 4, n2 = 2 * K_ * CIN_ / 4;
        const float* src; int off;
        if (i4 < n1)      { src = Wq; off = i4; }
        else if (i4 < n2) { src = Wk; off = i4 - n1; }
        else              { src = Wv; off = i4 - n2; }
        float4 f = ((const float4*)src)[off];
        ushort4 h;
        h.x = f2bf(f.x); h.y = f2bf(f.y); h.z = f2bf(f.z); h.w = f2bf(f.w);
        *(ushort4*)(Wb + (size_t)i4 * 4) = h;
    }
}

// ---------------------------------------------------------------------------
// proj_mfma3: bf16 MFMA projection + fused BN channel stats (atomics).
// ---------------------------------------------------------------------------
__global__ __launch_bounds__(256) void proj_mfma3(
    const unsigned short* __restrict__ xT, const unsigned short* __restrict__ cT,
    const unsigned short* __restrict__ Wb,
    const float* __restrict__ bq, const float* __restrict__ bk,
    const float* __restrict__ bv,
    float* __restrict__ k_buf, float* __restrict__ v_raw,
    unsigned short* __restrict__ qT, float* __restrict__ stat)
{
    __shared__ unsigned short Wt[64][72];
    __shared__ unsigned short Xt[128][72];
    const int tid = threadIdx.x;
    const int b = blockIdx.z, t0 = blockIdx.x * 128, yb = blockIdx.y;

    const unsigned short* in; const unsigned short* W; const float* bias;
    float* outp = nullptr; int ch0 = 0; float* ssum = nullptr; float* ssq = nullptr;
    if (yb == 0)      { in = xT; W = Wb;             bias = bq;
                        ssum = stat; ssq = stat + 64; ch0 = 0; }
    else if (yb == 1) { in = cT; W = Wb + K_ * CIN_; bias = bk;
                        outp = k_buf + (size_t)b * K_ * T_; }
    else { int m0 = (yb - 2) * 64; in = cT;
           W = Wb + 2 * K_ * CIN_ + (size_t)m0 * CIN_; bias = bv + m0;
           outp = v_raw + ((size_t)b * V_ + m0) * T_;
           ssum = stat + 128; ssq = stat + 384; ch0 = m0; }

    const int lane = tid & 63, w = tid >> 6;
    const int col = lane & 15, quad = lane >> 4;
    const int wm = tid >> 2, wp = tid & 3;
    const int xt = tid >> 1, xh = tid & 1;

    f32x4 acc[8];
    #pragma unroll
    for (int j = 0; j < 8; j++) acc[j] = (f32x4){0.f, 0.f, 0.f, 0.f};

    for (int c0 = 0; c0 < CIN_; c0 += 64) {
        {
            const unsigned short* ws = W + (size_t)wm * CIN_ + c0 + wp * 16;
            *(bf16x8*)&Wt[wm][wp * 16]     = *(const bf16x8*)(ws);
            *(bf16x8*)&Wt[wm][wp * 16 + 8] = *(const bf16x8*)(ws + 8);
            const unsigned short* xs = in + ((size_t)b * T_ + t0 + xt) * CIN_ + c0 + xh * 32;
            #pragma unroll
            for (int u = 0; u < 4; u++)
                *(bf16x8*)&Xt[xt][xh * 32 + 8 * u] = *(const bf16x8*)(xs + 8 * u);
        }
        __syncthreads();
        #pragma unroll
        for (int ks = 0; ks < 2; ks++) {
            const int kc = ks * 32 + quad * 8;
            bf16x8 af = *(bf16x8*)&Wt[w * 16 + col][kc];
            #pragma unroll
            for (int j = 0; j < 8; j++) {
                bf16x8 bfr = *(bf16x8*)&Xt[j * 16 + col][kc];
                acc[j] = __builtin_amdgcn_mfma_f32_16x16x32_bf16(af, bfr, acc[j], 0, 0, 0);
            }
        }
        __syncthreads();
    }

    float bias_v[4], s[4], sq[4];
    #pragma unroll
    for (int r = 0; r < 4; r++) {
        bias_v[r] = bias[w * 16 + quad * 4 + r];
        s[r] = 0.f; sq[r] = 0.f;
    }
    #pragma unroll
    for (int j = 0; j < 8; j++) {
        float o[4];
        #pragma unroll
        for (int r = 0; r < 4; r++) {
            o[r] = acc[j][r] + bias_v[r];
            s[r] += o[r]; sq[r] += o[r] * o[r];
        }
        if (yb == 0) {
            ushort4 h;
            h.x = f2bf(o[0]); h.y = f2bf(o[1]); h.z = f2bf(o[2]); h.w = f2bf(o[3]);
            *(ushort4*)(qT + ((size_t)b * T_ + t0 + j * 16 + col) * K_ + w * 16 + quad * 4) = h;
        } else {
            #pragma unroll
            for (int r = 0; r < 4; r++)
                outp[(size_t)(w * 16 + quad * 4 + r) * T_ + t0 + j * 16 + col] = o[r];
        }
    }
    if (ssum) {
        #pragma unroll
        for (int r = 0; r < 4; r++) {
            float sv = s[r], qv = sq[r];
            #pragma unroll
            for (int off = 1; off < 16; off <<= 1) {
                sv += __shfl_xor(sv, off, 64);
                qv += __shfl_xor(qv, off, 64);
            }
            if (col == 0) {
                int ch = ch0 + w * 16 + quad * 4 + r;
                atomicAdd(&ssum[ch], sv);
                atomicAdd(&ssq[ch], qv);
            }
        }
    }
}

// ---------------------------------------------------------------------------
// Softmax over T, in place.  512 blocks (one per (b,k) row).
// ---------------------------------------------------------------------------
__global__ __launch_bounds__(256) void softmax_kernel(float* __restrict__ k_buf)
{
    __shared__ float red[256];
    const int tid = threadIdx.x;
    float4* row = (float4*)(k_buf + (size_t)blockIdx.x * T_);
    float4 v = row[tid];
    float mx = fmaxf(fmaxf(v.x, v.y), fmaxf(v.z, v.w));
    red[tid] = mx; __syncthreads();
    for (int st = 128; st > 0; st >>= 1) {
        if (tid < st) red[tid] = fmaxf(red[tid], red[tid + st]);
        __syncthreads();
    }
    mx = red[0]; __syncthreads();
    float4 e;
    e.x = __expf(v.x - mx); e.y = __expf(v.y - mx);
    e.z = __expf(v.z - mx); e.w = __expf(v.w - mx);
    red[tid] = e.x + e.y + e.z + e.w; __syncthreads();
    for (int st = 128; st > 0; st >>= 1) {
        if (tid < st) red[tid] += red[tid + st];
        __syncthreads();
    }
    float inv = 1.f / red[0];
    e.x *= inv; e.y *= inv; e.z *= inv; e.w *= inv;
    row[tid] = e;
}

// ---------------------------------------------------------------------------
// lambda3: clp[b,tc,k,v] = sum_{t in chunk} nk[b,k,t]*v_raw[b,v,t]
// 512 blocks; plain partial stores, no atomics.
// ---------------------------------------------------------------------------
__global__ __launch_bounds__(256) void lambda_kernel3(
    const float* __restrict__ k_buf, const float* __restrict__ v_raw,
    float* __restrict__ clp)
{
    __shared__ __align__(16) float nks[K_][68];
    __shared__ __align__(16) float vls[64][68];
    const int tid = threadIdx.x;
    const int b = blockIdx.z, v0 = blockIdx.y * 64, tc = blockIdx.x, t0 = tc * 64;
    {
        const int r = tid >> 2, q = tid & 3;
        const float* nrow = k_buf + ((size_t)b * K_ + r) * T_ + t0;
        const float* vrow = v_raw + ((size_t)b * V_ + v0 + r) * T_ + t0;
        #pragma unroll
        for (int i = 0; i < 4; i++) {
            int c4 = q + 4 * i;
            float4 g = *(const float4*)(nrow + 4 * c4);
            *(float4*)&nks[r][4 * c4] = g;
            float4 h = *(const float4*)(vrow + 4 * c4);
            vls[4 * c4 + 0][r] = h.x; vls[4 * c4 + 1][r] = h.y;
            vls[4 * c4 + 2][r] = h.z; vls[4 * c4 + 3][r] = h.w;
        }
    }
    __syncthreads();
    const int tv = tid & 15, tk = tid >> 4;
    float4 acc[4];
    #pragma unroll
    for (int i = 0; i < 4; i++) acc[i] = make_float4(0.f, 0.f, 0.f, 0.f);
    for (int tt = 0; tt < 16; tt++) {
        float4 w0 = *(float4*)&vls[4 * tt + 0][4 * tv];
        float4 w1 = *(float4*)&vls[4 * tt + 1][4 * tv];
        float4 w2 = *(float4*)&vls[4 * tt + 2][4 * tv];
        float4 w3 = *(float4*)&vls[4 * tt + 3][4 * tv];
        #pragma unroll
        for (int i = 0; i < 4; i++) {
            float4 n = *(float4*)&nks[4 * tk + i][4 * tt];
            acc[i] += w0 * n.x + w1 * n.y + w2 * n.z + w3 * n.w;
        }
    }
    #pragma unroll
    for (int i = 0; i < 4; i++)
        *(float4*)&clp[(((size_t)b * NTC_ + tc) * K_ + 4 * tk + i) * V_ + v0 + 4 * tv] = acc[i];
}

// ---------------------------------------------------------------------------
// prep_cl2: sum clp partials; BN params inline from stat.
// ---------------------------------------------------------------------------
__global__ __launch_bounds__(256) void prep_cl_kernel2(
    const float* __restrict__ clp, const float* __restrict__ stat,
    const float* __restrict__ gq, const float* __restrict__ betaq,
    const float* __restrict__ gv, const float* __restrict__ betav,
    unsigned short* __restrict__ clb2, float* __restrict__ hterm)
{
    __shared__ float qsc[64], qsh[64], red[4][64];
    const int tid = threadIdx.x;
    const int b = blockIdx.y, v0 = blockIdx.x * 64;
    const float inv_n = 1.f / (B_ * T_);
    if (tid < 64) {
        float mean = stat[tid] * inv_n;
        float var  = stat[64 + tid] * inv_n - mean * mean;
        float sc = gq[tid] * rsqrtf(var + EPS_);
        qsc[tid] = sc; qsh[tid] = betaq[tid] - mean * sc;
    }
    const int vl = tid & 63, kq = tid >> 6;
    const int c = v0 + vl;
    float vmean = stat[128 + c] * inv_n;
    float vvar  = stat[384 + c] * inv_n - vmean * vmean;
    float vsv = gv[c] * rsqrtf(vvar + EPS_);
    float vhv = betav[c] - vmean * vsv;
    __syncthreads();
    float h = 0.f;
    for (int kk = 0; kk < 16; kk++) {
        int k = kq * 16 + kk;
        float a = 0.f;
        #pragma unroll
        for (int tc = 0; tc < NTC_; tc++)
            a += clp[(((size_t)b * NTC_ + tc) * K_ + k) * V_ + c];
        float clbv = a * vsv + vhv;
        h += qsh[k] * clbv;
        clb2[((size_t)b * V_ + c) * K_ + k] = f2bf(clbv * qsc[k]);
    }
    red[kq][vl] = h;
    __syncthreads();
    if (tid < 64)
        hterm[(size_t)b * V_ + v0 + tid] =
            red[0][tid] + red[1][tid] + red[2][tid] + red[3][tid];
}

// ---------------------------------------------------------------------------
// out4: fused qp + content-MFMA + conv epilogue (unchanged).
// ---------------------------------------------------------------------------
__global__ __launch_bounds__(256) void out_kernel4(
    const unsigned short* __restrict__ qT, const unsigned short* __restrict__ clb2,
    const float* __restrict__ hterm, const float* __restrict__ v_raw,
    const float* __restrict__ stat,
    const float* __restrict__ gq, const float* __restrict__ betaq,
    const float* __restrict__ gv, const float* __restrict__ betav,
    const float* __restrict__ pos_w, const float* __restrict__ pos_b,
    float* __restrict__ out)
{
    __shared__ unsigned short qTt[64][72];
    __shared__ unsigned short clv[64][72];
    __shared__ float vs2T[88][68];
    __shared__ float qpt[64][24];
    __shared__ float pws[64][24];
    __shared__ float qsc[64], qsh[64];
    __shared__ float consts[24];
    __shared__ float hvs[64];
    const int tid = threadIdx.x;
    const int b = blockIdx.z, v0 = blockIdx.y * 64, t0 = blockIdx.x * 64;
    const float inv_n = 1.f / (B_ * T_);

    if (tid < 64) {
        float mean = stat[tid] * inv_n;
        float var  = stat[64 + tid] * inv_n - mean * mean;
        float sc = gq[tid] * rsqrtf(var + EPS_);
        qsc[tid] = sc; qsh[tid] = betaq[tid] - mean * sc;
        hvs[tid] = hterm[(size_t)b * V_ + v0 + tid];
    }
    {
        const int rl = tid >> 2, part = tid & 3;
        const unsigned short* qs = qT + ((size_t)b * T_ + t0 + rl) * K_ + part * 16;
        *(bf16x8*)&qTt[rl][part * 16]     = *(const bf16x8*)(qs);
        *(bf16x8*)&qTt[rl][part * 16 + 8] = *(const bf16x8*)(qs + 8);
        const unsigned short* cs = clb2 + ((size_t)b * V_ + v0 + rl) * K_ + part * 16;
        *(bf16x8*)&clv[rl][part * 16]     = *(const bf16x8*)(cs);
        *(bf16x8*)&clv[rl][part * 16 + 8] = *(const bf16x8*)(cs + 8);
    }
    {
        const int vl = tid >> 2, qq = tid & 3;
        const int c = v0 + vl;
        float vmean = stat[128 + c] * inv_n;
        float vvar  = stat[384 + c] * inv_n - vmean * vmean;
        float vsv = gv[c] * rsqrtf(vvar + EPS_);
        float vhv = betav[c] - vmean * vsv;
        const float* vrow = v_raw + ((size_t)b * V_ + c) * T_;
        #pragma unroll
        for (int i = 0; i < 22; i++) {
            int cc = qq + 4 * i;
            if (cc < 86) {
                int t = t0 + cc - 11;
                vs2T[cc][vl] = (t >= 0 && t < T_) ? vrow[t] * vsv + vhv : 0.f;
            }
        }
    }
    __syncthreads();

    for (int idx = tid; idx < K_ * 24; idx += 256) {
        int k = idx / 24, s = idx % 24;
        pws[k][s] = qsc[k] * (s < KS_ ? pos_w[k * KS_ + s] : pos_b[k]);
    }
    if (tid < 24) {
        float cs = 0.f;
        for (int k = 0; k < K_; k++)
            cs += qsh[k] * (tid < KS_ ? pos_w[k * KS_ + tid] : pos_b[k]);
        consts[tid] = cs;
    }
    __syncthreads();

    {
        const int t = tid >> 2, sg = tid & 3, s0 = sg * 6;
        float a[6];
        #pragma unroll
        for (int u = 0; u < 6; u++) a[u] = consts[s0 + u];
        #pragma unroll
        for (int kb = 0; kb < 8; kb++) {
            bf16x8 qv = *(bf16x8*)&qTt[t][kb * 8];
            #pragma unroll
            for (int j = 0; j < 8; j++) {
                float q = bf2f((unsigned short)qv[j]);
                #pragma unroll
                for (int u = 0; u < 6; u++) a[u] += q * pws[kb * 8 + j][s0 + u];
            }
        }
        #pragma unroll
        for (int u = 0; u < 6; u++) qpt[t][s0 + u] = a[u];
    }
    __syncthreads();

    const int lane = tid & 63, w = tid >> 6;
    const int col = lane & 15, quad = lane >> 4;

    f32x4 acc[4];
    #pragma unroll
    for (int tf = 0; tf < 4; tf++) acc[tf] = (f32x4){0.f, 0.f, 0.f, 0.f};

    #pragma unroll
    for (int ks = 0; ks < 2; ks++) {
        const int kc = ks * 32 + quad * 8;
        bf16x8 af = *(bf16x8*)&clv[w * 16 + col][kc];
        #pragma unroll
        for (int tf = 0; tf < 4; tf++) {
            bf16x8 bq = *(bf16x8*)&qTt[tf * 16 + col][kc];
            acc[tf] = __builtin_amdgcn_mfma_f32_16x16x32_bf16(af, bq, acc[tf], 0, 0, 0);
        }
    }

    const int vb = w * 16 + quad * 4;
    float4 hv4 = *(float4*)&hvs[vb];
    #pragma unroll
    for (int tf = 0; tf < 4; tf++) {
        const int lt = tf * 16 + col;
        float qv[24];
        #pragma unroll
        for (int u = 0; u < 6; u++)
            *(float4*)&qv[4 * u] = *(float4*)&qpt[lt][4 * u];
        float4 a; a.x = acc[tf][0]; a.y = acc[tf][1]; a.z = acc[tf][2]; a.w = acc[tf][3];
        #pragma unroll
        for (int s = 0; s < KS_; s++) {
            float4 wv = *(float4*)&vs2T[lt + s][vb];
            a.x += qv[s] * wv.x; a.y += qv[s] * wv.y;
            a.z += qv[s] * wv.z; a.w += qv[s] * wv.w;
        }
        float base = qv[23];
        a.x += base + hv4.x; a.y += base + hv4.y;
        a.z += base + hv4.z; a.w += base + hv4.w;
        float* ap = (float*)&a;
        #pragma unroll
        for (int r = 0; r < 4; r++)
            out[((size_t)b * V_ + v0 + vb + r) * T_ + t0 + lt] = ap[r];
    }
}

extern "C" void kernel_launch(void* const* d_in, const int* in_sizes, int n_in,
                              void* d_out, int out_size, void* d_ws, size_t ws_size,
                              hipStream_t stream)
{
    const float* x     = (const float*)d_in[0];
    const float* ctx   = (const float*)d_in[1];
    const float* Wq    = (const float*)d_in[2];
    const float* bq    = (const float*)d_in[3];
    const float* Wk    = (const float*)d_in[4];
    const float* bk    = (const float*)d_in[5];
    const float* Wv    = (const float*)d_in[6];
    const float* bv    = (const float*)d_in[7];
    const float* gq    = (const float*)d_in[8];
    const float* betaq = (const float*)d_in[9];
    const float* gv    = (const float*)d_in[10];
    const float* betav = (const float*)d_in[11];
    const float* pos_w = (const float*)d_in[12];
    const float* pos_b = (const float*)d_in[13];
    float* out = (float*)d_out;

    float* ws    = (float*)d_ws;
    float* k_buf = ws;                                   // B*K*T      = 524288
    float* v_raw = k_buf + (size_t)B_ * K_ * T_;         // B*V*T      = 2097152
    float* clp   = v_raw + (size_t)B_ * V_ * T_;         // B*NTC*K*V  = 2097152
    float* stat  = clp + (size_t)B_ * NTC_ * K_ * V_;    // 640
    float* hterm = stat + 640;                           // B*V = 2048
    unsigned short* xT   = (unsigned short*)(hterm + (size_t)B_ * V_);
    unsigned short* cT   = xT + (size_t)B_ * T_ * CIN_;
    unsigned short* Wb   = cT + (size_t)B_ * T_ * CIN_;
    unsigned short* qT   = Wb + (size_t)(2 * K_ + V_) * CIN_;
    unsigned short* clb2 = qT + (size_t)B_ * T_ * K_;

    prep_kernel<<<dim3(2048 + 192), 256, 0, stream>>>(
        x, ctx, Wq, Wk, Wv, xT, cT, Wb, stat);
    proj_mfma3<<<dim3(T_ / 128, 6, B_), 256, 0, stream>>>(
        xT, cT, Wb, bq, bk, bv, k_buf, v_raw, qT, stat);
    softmax_kernel<<<dim3(B_ * K_), 256, 0, stream>>>(k_buf);
    lambda_kernel3<<<dim3(NTC_, V_ / 64, B_), 256, 0, stream>>>(k_buf, v_raw, clp);
    prep_cl_kernel2<<<dim3(V_ / 64, B_), 256, 0, stream>>>(
        clp, stat, gq, betaq, gv, betav, clb2, hterm);
    out_kernel4<<<dim3(T_ / 64, V_ / 64, B_), 256, 0, stream>>>(
        qT, clb2, hterm, v_raw, stat, gq, betaq, gv, betav, pos_w, pos_b, out);
}

// Round 10
// 155.627 us; speedup vs baseline: 1.4328x; 1.0308x over previous
//
#include <hip/hip_runtime.h>
#include <math.h>

#define B_ 8
#define CIN_ 512
#define K_ 64
#define V_ 256
#define T_ 1024
#define KS_ 23
#define EPS_ 1e-5f
#define NTC_ 16   // lambda t-chunks (partials)

typedef __attribute__((ext_vector_type(8))) short bf16x8;
typedef __attribute__((ext_vector_type(4))) float f32x4;

__device__ __forceinline__ unsigned short f2bf(float f) {
    union { float f; unsigned u; } x; x.f = f;
    unsigned r = x.u + 0x7fffu + ((x.u >> 16) & 1u);   // RNE
    return (unsigned short)(r >> 16);
}
__device__ __forceinline__ float bf2f(unsigned short h) {
    union { unsigned u; float f; } x; x.u = ((unsigned)h) << 16;
    return x.f;
}

// ---------------------------------------------------------------------------
// prep: merged cvtT (blocks 0..2047) + prew (blocks 2048..2239).
// ---------------------------------------------------------------------------
__global__ __launch_bounds__(256) void prep_kernel(
    const float* __restrict__ x, const float* __restrict__ ctx,
    const float* __restrict__ Wq, const float* __restrict__ Wk,
    const float* __restrict__ Wv,
    unsigned short* __restrict__ xT, unsigned short* __restrict__ cT,
    unsigned short* __restrict__ Wb, float* __restrict__ stat)
{
    __shared__ unsigned short sh[64][72];
    const int tid = threadIdx.x;
    const int id = blockIdx.x;
    if (id < 2048) {
        const int t0 = (id & 15) * 64, c0 = ((id >> 4) & 7) * 64;
        const int z = id >> 7, b = z & 7, which = z >> 3;
        const float* src = which ? ctx : x;
        unsigned short* dst = which ? cT : xT;
        const int cl = tid >> 2, qq = tid & 3;
        const float* row = src + ((size_t)b * CIN_ + c0 + cl) * T_ + t0 + qq * 16;
        #pragma unroll
        for (int u = 0; u < 4; u++) {
            float4 f = *(const float4*)(row + 4 * u);
            sh[qq * 16 + 4 * u + 0][cl] = f2bf(f.x);
            sh[qq * 16 + 4 * u + 1][cl] = f2bf(f.y);
            sh[qq * 16 + 4 * u + 2][cl] = f2bf(f.z);
            sh[qq * 16 + 4 * u + 3][cl] = f2bf(f.w);
        }
        __syncthreads();
        const int tl = tid >> 2;
        unsigned short* orow = dst + ((size_t)b * T_ + t0 + tl) * CIN_ + c0 + qq * 16;
        *(bf16x8*)(orow)     = *(bf16x8*)&sh[tl][qq * 16];
        *(bf16x8*)(orow + 8) = *(bf16x8*)&sh[tl][qq * 16 + 8];
    } else {
        const int wid = id - 2048;
        if (wid == 0 && tid < 160)
            ((float4*)stat)[tid] = make_float4(0.f, 0.f, 0.f, 0.f);
        const int i4 = wid * 256 + tid;
        const int n1 = K_ * CIN_ / 4, n2 = 2 * K_ * CIN_ / 4;
        const float* src; int off;
        if (i4 < n1)      { src = Wq; off = i4; }
        else if (i4 < n2) { src = Wk; off = i4 - n1; }
        else              { src = Wv; off = i4 - n2; }
        float4 f = ((const float4*)src)[off];
        ushort4 h;
        h.x = f2bf(f.x); h.y = f2bf(f.y); h.z = f2bf(f.z); h.w = f2bf(f.w);
        *(ushort4*)(Wb + (size_t)i4 * 4) = h;
    }
}

// ---------------------------------------------------------------------------
// proj_mfma4: bf16 MFMA projection + fused epilogue reductions.
// yb==0: q -> qT bf16 + BN stats.  yb==1: k -> k_buf fp32 (raw) + per-128t
// ONLINE-SOFTMAX partials kml[b][k][seg]={m,l}.  yb==2..5: v + BN stats.
// ---------------------------------------------------------------------------
__global__ __launch_bounds__(256) void proj_mfma4(
    const unsigned short* __restrict__ xT, const unsigned short* __restrict__ cT,
    const unsigned short* __restrict__ Wb,
    const float* __restrict__ bq, const float* __restrict__ bk,
    const float* __restrict__ bv,
    float* __restrict__ k_buf, float* __restrict__ v_raw,
    unsigned short* __restrict__ qT, float* __restrict__ stat,
    float* __restrict__ kml)
{
    __shared__ unsigned short Wt[64][72];
    __shared__ unsigned short Xt[128][72];
    const int tid = threadIdx.x;
    const int b = blockIdx.z, t0 = blockIdx.x * 128, yb = blockIdx.y;

    const unsigned short* in; const unsigned short* W; const float* bias;
    float* outp = nullptr; int ch0 = 0; float* ssum = nullptr; float* ssq = nullptr;
    if (yb == 0)      { in = xT; W = Wb;             bias = bq;
                        ssum = stat; ssq = stat + 64; ch0 = 0; }
    else if (yb == 1) { in = cT; W = Wb + K_ * CIN_; bias = bk;
                        outp = k_buf + (size_t)b * K_ * T_; }
    else { int m0 = (yb - 2) * 64; in = cT;
           W = Wb + 2 * K_ * CIN_ + (size_t)m0 * CIN_; bias = bv + m0;
           outp = v_raw + ((size_t)b * V_ + m0) * T_;
           ssum = stat + 128; ssq = stat + 384; ch0 = m0; }

    const int lane = tid & 63, w = tid >> 6;
    const int col = lane & 15, quad = lane >> 4;
    const int wm = tid >> 2, wp = tid & 3;
    const int xt = tid >> 1, xh = tid & 1;

    f32x4 acc[8];
    #pragma unroll
    for (int j = 0; j < 8; j++) acc[j] = (f32x4){0.f, 0.f, 0.f, 0.f};

    for (int c0 = 0; c0 < CIN_; c0 += 64) {
        {
            const unsigned short* ws = W + (size_t)wm * CIN_ + c0 + wp * 16;
            *(bf16x8*)&Wt[wm][wp * 16]     = *(const bf16x8*)(ws);
            *(bf16x8*)&Wt[wm][wp * 16 + 8] = *(const bf16x8*)(ws + 8);
            const unsigned short* xs = in + ((size_t)b * T_ + t0 + xt) * CIN_ + c0 + xh * 32;
            #pragma unroll
            for (int u = 0; u < 4; u++)
                *(bf16x8*)&Xt[xt][xh * 32 + 8 * u] = *(const bf16x8*)(xs + 8 * u);
        }
        __syncthreads();
        #pragma unroll
        for (int ks = 0; ks < 2; ks++) {
            const int kc = ks * 32 + quad * 8;
            bf16x8 af = *(bf16x8*)&Wt[w * 16 + col][kc];
            #pragma unroll
            for (int j = 0; j < 8; j++) {
                bf16x8 bfr = *(bf16x8*)&Xt[j * 16 + col][kc];
                acc[j] = __builtin_amdgcn_mfma_f32_16x16x32_bf16(af, bfr, acc[j], 0, 0, 0);
            }
        }
        __syncthreads();
    }

    float bias_v[4], s[4], sq[4], mr[4], lr[4];
    #pragma unroll
    for (int r = 0; r < 4; r++) {
        bias_v[r] = bias[w * 16 + quad * 4 + r];
        s[r] = 0.f; sq[r] = 0.f; mr[r] = -1e30f; lr[r] = 0.f;
    }
    #pragma unroll
    for (int j = 0; j < 8; j++) {
        float o[4];
        #pragma unroll
        for (int r = 0; r < 4; r++) {
            o[r] = acc[j][r] + bias_v[r];
            s[r] += o[r]; sq[r] += o[r] * o[r];
        }
        if (yb == 0) {
            ushort4 h;
            h.x = f2bf(o[0]); h.y = f2bf(o[1]); h.z = f2bf(o[2]); h.w = f2bf(o[3]);
            *(ushort4*)(qT + ((size_t)b * T_ + t0 + j * 16 + col) * K_ + w * 16 + quad * 4) = h;
        } else {
            #pragma unroll
            for (int r = 0; r < 4; r++)
                outp[(size_t)(w * 16 + quad * 4 + r) * T_ + t0 + j * 16 + col] = o[r];
            if (yb == 1) {
                #pragma unroll
                for (int r = 0; r < 4; r++) {
                    float mn = fmaxf(mr[r], o[r]);
                    lr[r] = lr[r] * __expf(mr[r] - mn) + __expf(o[r] - mn);
                    mr[r] = mn;
                }
            }
        }
    }
    if (yb == 1) {
        // cross-lane online-softmax combine over the 16 cols (same rows)
        #pragma unroll
        for (int r = 0; r < 4; r++) {
            float m = mr[r], l = lr[r];
            #pragma unroll
            for (int off = 1; off < 16; off <<= 1) {
                float mo = __shfl_xor(m, off, 64);
                float lo = __shfl_xor(l, off, 64);
                float mn = fmaxf(m, mo);
                l = l * __expf(m - mn) + lo * __expf(mo - mn);
                m = mn;
            }
            if (col == 0) {
                int row = w * 16 + quad * 4 + r;
                float* p = kml + (((size_t)b * K_ + row) * 8 + (t0 >> 7)) * 2;
                p[0] = m; p[1] = l;
            }
        }
    } else {
        #pragma unroll
        for (int r = 0; r < 4; r++) {
            float sv = s[r], qv = sq[r];
            #pragma unroll
            for (int off = 1; off < 16; off <<= 1) {
                sv += __shfl_xor(sv, off, 64);
                qv += __shfl_xor(qv, off, 64);
            }
            if (col == 0) {
                int ch = ch0 + w * 16 + quad * 4 + r;
                atomicAdd(&ssum[ch], sv);
                atomicAdd(&ssq[ch], qv);
            }
        }
    }
}

// ---------------------------------------------------------------------------
// lambda4: combine kml partials -> (m, 1/l) per row; stage RAW k_buf with
// exp((k-m))*l^-1 inline; clp[b,tc,k,v] partials.  512 blocks, no atomics.
// ---------------------------------------------------------------------------
__global__ __launch_bounds__(256) void lambda_kernel4(
    const float* __restrict__ k_buf, const float* __restrict__ v_raw,
    const float* __restrict__ kml, float* __restrict__ clp)
{
    __shared__ __align__(16) float nks[K_][68];
    __shared__ __align__(16) float vls[64][68];
    __shared__ float mrow[64], lrow[64];
    const int tid = threadIdx.x;
    const int b = blockIdx.z, v0 = blockIdx.y * 64, tc = blockIdx.x, t0 = tc * 64;

    if (tid < 64) {
        const float2* p = (const float2*)(kml + ((size_t)b * K_ + tid) * 16);
        float m = -1e30f, l = 0.f;
        #pragma unroll
        for (int sgi = 0; sgi < 8; sgi++) {
            float2 ml = p[sgi];
            float mn = fmaxf(m, ml.x);
            l = l * __expf(m - mn) + ml.y * __expf(ml.x - mn);
            m = mn;
        }
        mrow[tid] = m; lrow[tid] = 1.f / l;
    }
    __syncthreads();
    {
        const int r = tid >> 2, q = tid & 3;
        const float* nrow = k_buf + ((size_t)b * K_ + r) * T_ + t0;
        const float* vrow = v_raw + ((size_t)b * V_ + v0 + r) * T_ + t0;
        const float mr = mrow[r], li = lrow[r];
        #pragma unroll
        for (int i = 0; i < 4; i++) {
            int c4 = q + 4 * i;
            float4 g = *(const float4*)(nrow + 4 * c4);
            g.x = __expf(g.x - mr) * li; g.y = __expf(g.y - mr) * li;
            g.z = __expf(g.z - mr) * li; g.w = __expf(g.w - mr) * li;
            *(float4*)&nks[r][4 * c4] = g;
            float4 h = *(const float4*)(vrow + 4 * c4);
            vls[4 * c4 + 0][r] = h.x; vls[4 * c4 + 1][r] = h.y;
            vls[4 * c4 + 2][r] = h.z; vls[4 * c4 + 3][r] = h.w;
        }
    }
    __syncthreads();
    const int tv = tid & 15, tk = tid >> 4;
    float4 acc[4];
    #pragma unroll
    for (int i = 0; i < 4; i++) acc[i] = make_float4(0.f, 0.f, 0.f, 0.f);
    for (int tt = 0; tt < 16; tt++) {
        float4 w0 = *(float4*)&vls[4 * tt + 0][4 * tv];
        float4 w1 = *(float4*)&vls[4 * tt + 1][4 * tv];
        float4 w2 = *(float4*)&vls[4 * tt + 2][4 * tv];
        float4 w3 = *(float4*)&vls[4 * tt + 3][4 * tv];
        #pragma unroll
        for (int i = 0; i < 4; i++) {
            float4 n = *(float4*)&nks[4 * tk + i][4 * tt];
            acc[i] += w0 * n.x + w1 * n.y + w2 * n.z + w3 * n.w;
        }
    }
    #pragma unroll
    for (int i = 0; i < 4; i++)
        *(float4*)&clp[(((size_t)b * NTC_ + tc) * K_ + 4 * tk + i) * V_ + v0 + 4 * tv] = acc[i];
}

// ---------------------------------------------------------------------------
// prep_cl2: sum clp partials; BN params inline from stat.  (unchanged)
// ---------------------------------------------------------------------------
__global__ __launch_bounds__(256) void prep_cl_kernel2(
    const float* __restrict__ clp, const float* __restrict__ stat,
    const float* __restrict__ gq, const float* __restrict__ betaq,
    const float* __restrict__ gv, const float* __restrict__ betav,
    unsigned short* __restrict__ clb2, float* __restrict__ hterm)
{
    __shared__ float qsc[64], qsh[64], red[4][64];
    const int tid = threadIdx.x;
    const int b = blockIdx.y, v0 = blockIdx.x * 64;
    const float inv_n = 1.f / (B_ * T_);
    if (tid < 64) {
        float mean = stat[tid] * inv_n;
        float var  = stat[64 + tid] * inv_n - mean * mean;
        float sc = gq[tid] * rsqrtf(var + EPS_);
        qsc[tid] = sc; qsh[tid] = betaq[tid] - mean * sc;
    }
    const int vl = tid & 63, kq = tid >> 6;
    const int c = v0 + vl;
    float vmean = stat[128 + c] * inv_n;
    float vvar  = stat[384 + c] * inv_n - vmean * vmean;
    float vsv = gv[c] * rsqrtf(vvar + EPS_);
    float vhv = betav[c] - vmean * vsv;
    __syncthreads();
    float h = 0.f;
    for (int kk = 0; kk < 16; kk++) {
        int k = kq * 16 + kk;
        float a = 0.f;
        #pragma unroll
        for (int tc = 0; tc < NTC_; tc++)
            a += clp[(((size_t)b * NTC_ + tc) * K_ + k) * V_ + c];
        float clbv = a * vsv + vhv;
        h += qsh[k] * clbv;
        clb2[((size_t)b * V_ + c) * K_ + k] = f2bf(clbv * qsc[k]);
    }
    red[kq][vl] = h;
    __syncthreads();
    if (tid < 64)
        hterm[(size_t)b * V_ + v0 + tid] =
            red[0][tid] + red[1][tid] + red[2][tid] + red[3][tid];
}

// ---------------------------------------------------------------------------
// out4: fused qp + content-MFMA + conv epilogue (unchanged).
// ---------------------------------------------------------------------------
__global__ __launch_bounds__(256) void out_kernel4(
    const unsigned short* __restrict__ qT, const unsigned short* __restrict__ clb2,
    const float* __restrict__ hterm, const float* __restrict__ v_raw,
    const float* __restrict__ stat,
    const float* __restrict__ gq, const float* __restrict__ betaq,
    const float* __restrict__ gv, const float* __restrict__ betav,
    const float* __restrict__ pos_w, const float* __restrict__ pos_b,
    float* __restrict__ out)
{
    __shared__ unsigned short qTt[64][72];
    __shared__ unsigned short clv[64][72];
    __shared__ float vs2T[88][68];
    __shared__ float qpt[64][24];
    __shared__ float pws[64][24];
    __shared__ float qsc[64], qsh[64];
    __shared__ float consts[24];
    __shared__ float hvs[64];
    const int tid = threadIdx.x;
    const int b = blockIdx.z, v0 = blockIdx.y * 64, t0 = blockIdx.x * 64;
    const float inv_n = 1.f / (B_ * T_);

    if (tid < 64) {
        float mean = stat[tid] * inv_n;
        float var  = stat[64 + tid] * inv_n - mean * mean;
        float sc = gq[tid] * rsqrtf(var + EPS_);
        qsc[tid] = sc; qsh[tid] = betaq[tid] - mean * sc;
        hvs[tid] = hterm[(size_t)b * V_ + v0 + tid];
    }
    {
        const int rl = tid >> 2, part = tid & 3;
        const unsigned short* qs = qT + ((size_t)b * T_ + t0 + rl) * K_ + part * 16;
        *(bf16x8*)&qTt[rl][part * 16]     = *(const bf16x8*)(qs);
        *(bf16x8*)&qTt[rl][part * 16 + 8] = *(const bf16x8*)(qs + 8);
        const unsigned short* cs = clb2 + ((size_t)b * V_ + v0 + rl) * K_ + part * 16;
        *(bf16x8*)&clv[rl][part * 16]     = *(const bf16x8*)(cs);
        *(bf16x8*)&clv[rl][part * 16 + 8] = *(const bf16x8*)(cs + 8);
    }
    {
        const int vl = tid >> 2, qq = tid & 3;
        const int c = v0 + vl;
        float vmean = stat[128 + c] * inv_n;
        float vvar  = stat[384 + c] * inv_n - vmean * vmean;
        float vsv = gv[c] * rsqrtf(vvar + EPS_);
        float vhv = betav[c] - vmean * vsv;
        const float* vrow = v_raw + ((size_t)b * V_ + c) * T_;
        #pragma unroll
        for (int i = 0; i < 22; i++) {
            int cc = qq + 4 * i;
            if (cc < 86) {
                int t = t0 + cc - 11;
                vs2T[cc][vl] = (t >= 0 && t < T_) ? vrow[t] * vsv + vhv : 0.f;
            }
        }
    }
    __syncthreads();

    for (int idx = tid; idx < K_ * 24; idx += 256) {
        int k = idx / 24, s = idx % 24;
        pws[k][s] = qsc[k] * (s < KS_ ? pos_w[k * KS_ + s] : pos_b[k]);
    }
    if (tid < 24) {
        float cs = 0.f;
        for (int k = 0; k < K_; k++)
            cs += qsh[k] * (tid < KS_ ? pos_w[k * KS_ + tid] : pos_b[k]);
        consts[tid] = cs;
    }
    __syncthreads();

    {
        const int t = tid >> 2, sg = tid & 3, s0 = sg * 6;
        float a[6];
        #pragma unroll
        for (int u = 0; u < 6; u++) a[u] = consts[s0 + u];
        #pragma unroll
        for (int kb = 0; kb < 8; kb++) {
            bf16x8 qv = *(bf16x8*)&qTt[t][kb * 8];
            #pragma unroll
            for (int j = 0; j < 8; j++) {
                float q = bf2f((unsigned short)qv[j]);
                #pragma unroll
                for (int u = 0; u < 6; u++) a[u] += q * pws[kb * 8 + j][s0 + u];
            }
        }
        #pragma unroll
        for (int u = 0; u < 6; u++) qpt[t][s0 + u] = a[u];
    }
    __syncthreads();

    const int lane = tid & 63, w = tid >> 6;
    const int col = lane & 15, quad = lane >> 4;

    f32x4 acc[4];
    #pragma unroll
    for (int tf = 0; tf < 4; tf++) acc[tf] = (f32x4){0.f, 0.f, 0.f, 0.f};

    #pragma unroll
    for (int ks = 0; ks < 2; ks++) {
        const int kc = ks * 32 + quad * 8;
        bf16x8 af = *(bf16x8*)&clv[w * 16 + col][kc];
        #pragma unroll
        for (int tf = 0; tf < 4; tf++) {
            bf16x8 bq = *(bf16x8*)&qTt[tf * 16 + col][kc];
            acc[tf] = __builtin_amdgcn_mfma_f32_16x16x32_bf16(af, bq, acc[tf], 0, 0, 0);
        }
    }

    const int vb = w * 16 + quad * 4;
    float4 hv4 = *(float4*)&hvs[vb];
    #pragma unroll
    for (int tf = 0; tf < 4; tf++) {
        const int lt = tf * 16 + col;
        float qv[24];
        #pragma unroll
        for (int u = 0; u < 6; u++)
            *(float4*)&qv[4 * u] = *(float4*)&qpt[lt][4 * u];
        float4 a; a.x = acc[tf][0]; a.y = acc[tf][1]; a.z = acc[tf][2]; a.w = acc[tf][3];
        #pragma unroll
        for (int s = 0; s < KS_; s++) {
            float4 wv = *(float4*)&vs2T[lt + s][vb];
            a.x += qv[s] * wv.x; a.y += qv[s] * wv.y;
            a.z += qv[s] * wv.z; a.w += qv[s] * wv.w;
        }
        float base = qv[23];
        a.x += base + hv4.x; a.y += base + hv4.y;
        a.z += base + hv4.z; a.w += base + hv4.w;
        float* ap = (float*)&a;
        #pragma unroll
        for (int r = 0; r < 4; r++)
            out[((size_t)b * V_ + v0 + vb + r) * T_ + t0 + lt] = ap[r];
    }
}

extern "C" void kernel_launch(void* const* d_in, const int* in_sizes, int n_in,
                              void* d_out, int out_size, void* d_ws, size_t ws_size,
                              hipStream_t stream)
{
    const float* x     = (const float*)d_in[0];
    const float* ctx   = (const float*)d_in[1];
    const float* Wq    = (const float*)d_in[2];
    const float* bq    = (const float*)d_in[3];
    const float* Wk    = (const float*)d_in[4];
    const float* bk    = (const float*)d_in[5];
    const float* Wv    = (const float*)d_in[6];
    const float* bv    = (const float*)d_in[7];
    const float* gq    = (const float*)d_in[8];
    const float* betaq = (const float*)d_in[9];
    const float* gv    = (const float*)d_in[10];
    const float* betav = (const float*)d_in[11];
    const float* pos_w = (const float*)d_in[12];
    const float* pos_b = (const float*)d_in[13];
    float* out = (float*)d_out;

    float* ws    = (float*)d_ws;
    float* k_buf = ws;                                   // B*K*T      = 524288
    float* v_raw = k_buf + (size_t)B_ * K_ * T_;         // B*V*T      = 2097152
    float* clp   = v_raw + (size_t)B_ * V_ * T_;         // B*NTC*K*V  = 2097152
    float* stat  = clp + (size_t)B_ * NTC_ * K_ * V_;    // 640
    float* hterm = stat + 640;                           // B*V = 2048
    float* kml   = hterm + (size_t)B_ * V_;              // B*K*8*2 = 8192
    unsigned short* xT   = (unsigned short*)(kml + (size_t)B_ * K_ * 16);
    unsigned short* cT   = xT + (size_t)B_ * T_ * CIN_;
    unsigned short* Wb   = cT + (size_t)B_ * T_ * CIN_;
    unsigned short* qT   = Wb + (size_t)(2 * K_ + V_) * CIN_;
    unsigned short* clb2 = qT + (size_t)B_ * T_ * K_;

    prep_kernel<<<dim3(2048 + 192), 256, 0, stream>>>(
        x, ctx, Wq, Wk, Wv, xT, cT, Wb, stat);
    proj_mfma4<<<dim3(T_ / 128, 6, B_), 256, 0, stream>>>(
        xT, cT, Wb, bq, bk, bv, k_buf, v_raw, qT, stat, kml);
    lambda_kernel4<<<dim3(NTC_, V_ / 64, B_), 256, 0, stream>>>(k_buf, v_raw, kml, clp);
    prep_cl_kernel2<<<dim3(V_ / 64, B_), 256, 0, stream>>>(
        clp, stat, gq, betaq, gv, betav, clb2, hterm);
    out_kernel4<<<dim3(T_ / 64, V_ / 64, B_), 256, 0, stream>>>(
        qT, clb2, hterm, v_raw, stat, gq, betaq, gv, betav, pos_w, pos_b, out);
}